// Round 1
// baseline (1941.830 us; speedup 1.0000x reference)
//
#include <hip/hip_runtime.h>

#define NN 100000
#define IND 128
#define HIDD 64
#define OUTD 16

// ---------------- degree ----------------
__global__ void k_deg(const int* __restrict__ dst, float* __restrict__ deg, int E) {
    int i = blockIdx.x * 256 + threadIdx.x;
    if (i < E) atomicAdd(&deg[dst[i]], 1.0f);
}

__global__ void k_deg_inv(float* __restrict__ deg) {
    int i = blockIdx.x * 256 + threadIdx.x;
    if (i < NN) deg[i] = 1.0f / fmaxf(deg[i], 1.0f);
}

// ---------------- GEMM1: out = x @ Wh.T  (Wh = W1l or W1r per blockIdx.y) ----------
// block: 256 thr; tile: 32 rows x 64 cols; K=128. LDS pads chosen so both
// the lw float4 read (row stride 68 floats = 272B, 16B aligned) and the
// lx scalar broadcast read ((4r+k)%32 distinct banks for the 4 row-groups
// of a wave) are conflict-free.
__global__ __launch_bounds__(256) void k_gemm1(const float* __restrict__ x,
                                               const float* __restrict__ W1l,
                                               const float* __restrict__ W1r,
                                               float* __restrict__ y1,
                                               float* __restrict__ xr) {
    __shared__ float lw[IND][68];   // lw[k][j] = Wh[j][k]
    __shared__ float lx[32][132];
    const int tid = threadIdx.x;
    const float* Wh = (blockIdx.y == 0) ? W1l : W1r;
    float* out = (blockIdx.y == 0) ? y1 : xr;
    for (int idx = tid; idx < 64 * 128; idx += 256) {
        int j = idx >> 7, k = idx & 127;
        lw[k][j] = Wh[idx];
    }
    const int row0 = blockIdx.x * 32;
    for (int i = 0; i < 4; ++i) {
        int f4 = i * 256 + tid;        // 1024 float4 = 32 rows * 32
        int r  = f4 >> 5;
        int k4 = (f4 & 31) << 2;
        int grow = row0 + r;
        float4 v = make_float4(0.f, 0.f, 0.f, 0.f);
        if (grow < NN) v = *(const float4*)(x + (size_t)grow * IND + k4);
        *(float4*)(&lx[r][k4]) = v;
    }
    __syncthreads();
    const int cg = tid & 15;   // 16 col-groups * 4 cols = 64 cols
    const int rl = tid >> 4;   // 16 rows per pass
    #pragma unroll
    for (int p = 0; p < 2; ++p) {
        int r = p * 16 + rl;
        int grow = row0 + r;
        float ax = 0.f, ay = 0.f, az = 0.f, aw = 0.f;
        #pragma unroll 8
        for (int k = 0; k < 128; ++k) {
            float xv = lx[r][k];
            float4 wv = *(const float4*)(&lw[k][cg << 2]);
            ax = fmaf(xv, wv.x, ax); ay = fmaf(xv, wv.y, ay);
            az = fmaf(xv, wv.z, az); aw = fmaf(xv, wv.w, aw);
        }
        if (grow < NN)
            *(float4*)(out + (size_t)grow * HIDD + (cg << 2)) = make_float4(ax, ay, az, aw);
    }
}

// ---------------- scatter-add: agg[dst] += y[src], F feats, 4 feats/thread ----------
template<int F, int LOG_G>
__global__ void k_scatter(const float* __restrict__ y, const int* __restrict__ src,
                          const int* __restrict__ dst, float* __restrict__ agg, int E) {
    int t = blockIdx.x * 256 + threadIdx.x;
    if (t >= (E << LOG_G)) return;
    int e = t >> LOG_G;
    int g = (t & ((1 << LOG_G) - 1)) << 2;
    int s = src[e], d = dst[e];
    float4 v = *(const float4*)(y + (size_t)s * F + g);
    float* p = agg + (size_t)d * F + g;
    atomicAdd(p + 0, v.x); atomicAdd(p + 1, v.y);
    atomicAdd(p + 2, v.z); atomicAdd(p + 3, v.w);
}

// ---------------- h = agg1*deg_inv + xr + b1l (in-place into agg1) + BN stats ------
__global__ __launch_bounds__(256) void k_h_stats(float* __restrict__ agg1,
        const float* __restrict__ xr, const float* __restrict__ b1l,
        const float* __restrict__ deg_inv, float* __restrict__ stats) {
    __shared__ float s1[4][64];
    __shared__ float s2[4][64];
    const int tid = threadIdx.x;
    const int f = tid & 63, g = tid >> 6;
    const int row0 = blockIdx.x * 128;
    const float bias = b1l[f];
    float a1 = 0.f, a2 = 0.f;
    for (int i = 0; i < 32; ++i) {
        int r = row0 + g + (i << 2);
        if (r < NN) {
            float di = deg_inv[r];
            size_t off = (size_t)r * 64 + f;
            float hv = fmaf(agg1[off], di, xr[off] + bias);
            agg1[off] = hv;
            a1 += hv; a2 = fmaf(hv, hv, a2);
        }
    }
    s1[g][f] = a1; s2[g][f] = a2;
    __syncthreads();
    if (g == 0) {
        float t1 = s1[0][f] + s1[1][f] + s1[2][f] + s1[3][f];
        float t2 = s2[0][f] + s2[1][f] + s2[2][f] + s2[3][f];
        atomicAdd(&stats[f], t1);
        atomicAdd(&stats[64 + f], t2);
    }
}

__global__ void k_bn_final(float* __restrict__ stats, const float* __restrict__ gamma,
                           const float* __restrict__ beta) {
    int f = threadIdx.x;
    float mu = stats[f] * (1.0f / NN);
    float var = stats[64 + f] * (1.0f / NN) - mu * mu;
    float sc = gamma[f] * rsqrtf(var + 1e-5f);
    stats[128 + f] = sc;
    stats[192 + f] = beta[f] - mu * sc;
}

// ---------------- GEMM2 (BN+ReLU fused into LDS staging): y2=hbn@W2l.T, hr2=hbn@W2r.T
__global__ __launch_bounds__(256) void k_gemm2(const float* __restrict__ h,
        const float* __restrict__ W2l, const float* __restrict__ W2r,
        const float* __restrict__ stats,
        float* __restrict__ y2, float* __restrict__ hr2) {
    __shared__ float lh[64][68];
    __shared__ float lw[64][36];   // lw[k][j], j<16 = W2l row j, j>=16 = W2r row j-16
    const int tid = threadIdx.x;
    for (int idx = tid; idx < 32 * 64; idx += 256) {
        int j = idx >> 6, k = idx & 63;
        lw[k][j] = (j < 16) ? W2l[idx] : W2r[idx - 1024];
    }
    const int row0 = blockIdx.x * 64;
    for (int i = 0; i < 4; ++i) {
        int f4 = i * 256 + tid;        // 1024 float4 = 64 rows * 16
        int r = f4 >> 4;
        int k4 = (f4 & 15) << 2;
        int grow = row0 + r;
        float4 v = make_float4(0.f, 0.f, 0.f, 0.f);
        if (grow < NN) v = *(const float4*)(h + (size_t)grow * 64 + k4);
        float4 sc = *(const float4*)(stats + 128 + k4);
        float4 sh = *(const float4*)(stats + 192 + k4);
        float4 o;
        o.x = fmaxf(fmaf(v.x, sc.x, sh.x), 0.f);
        o.y = fmaxf(fmaf(v.y, sc.y, sh.y), 0.f);
        o.z = fmaxf(fmaf(v.z, sc.z, sh.z), 0.f);
        o.w = fmaxf(fmaf(v.w, sc.w, sh.w), 0.f);
        *(float4*)(&lh[r][k4]) = o;
    }
    __syncthreads();
    const int cg = tid & 7;    // 8 col-groups * 4 = 32 cols (16 y2 + 16 hr2)
    const int rl = tid >> 3;   // 32 rows per pass
    #pragma unroll
    for (int p = 0; p < 2; ++p) {
        int r = p * 32 + rl;
        int grow = row0 + r;
        float ax = 0.f, ay = 0.f, az = 0.f, aw = 0.f;
        #pragma unroll
        for (int k = 0; k < 64; ++k) {
            float hv = lh[r][k];
            float4 wv = *(const float4*)(&lw[k][cg << 2]);
            ax = fmaf(hv, wv.x, ax); ay = fmaf(hv, wv.y, ay);
            az = fmaf(hv, wv.z, az); aw = fmaf(hv, wv.w, aw);
        }
        if (grow < NN) {
            int c = cg << 2;
            if (c < 16) *(float4*)(y2  + (size_t)grow * 16 + c)        = make_float4(ax, ay, az, aw);
            else        *(float4*)(hr2 + (size_t)grow * 16 + (c - 16)) = make_float4(ax, ay, az, aw);
        }
    }
}

// ---------------- epilogue: emb + logits straight to d_out ----------------
__global__ void k_emb(const float* __restrict__ agg2, const float* __restrict__ hr2,
                      const float* __restrict__ b2l, const float* __restrict__ deg_inv,
                      const float* __restrict__ Wc, const float* __restrict__ bc,
                      float* __restrict__ out) {
    int r = blockIdx.x * 256 + threadIdx.x;
    if (r >= NN) return;
    float di = deg_inv[r];
    float e[16];
    #pragma unroll
    for (int q = 0; q < 4; ++q) {
        float4 a = *(const float4*)(agg2 + (size_t)r * 16 + (q << 2));
        float4 h = *(const float4*)(hr2 + (size_t)r * 16 + (q << 2));
        float4 b = *(const float4*)(b2l + (q << 2));
        e[q * 4 + 0] = fmaf(a.x, di, h.x + b.x);
        e[q * 4 + 1] = fmaf(a.y, di, h.y + b.y);
        e[q * 4 + 2] = fmaf(a.z, di, h.z + b.z);
        e[q * 4 + 3] = fmaf(a.w, di, h.w + b.w);
    }
    float l0 = bc[0], l1 = bc[1];
    #pragma unroll
    for (int j = 0; j < 16; ++j) {
        l0 = fmaf(e[j], Wc[j], l0);
        l1 = fmaf(e[j], Wc[16 + j], l1);
    }
    out[(size_t)r * 2 + 0] = l0;
    out[(size_t)r * 2 + 1] = l1;
    float* oe = out + 2 * NN;
    #pragma unroll
    for (int q = 0; q < 4; ++q)
        *(float4*)(oe + (size_t)r * 16 + (q << 2)) =
            make_float4(e[q * 4], e[q * 4 + 1], e[q * 4 + 2], e[q * 4 + 3]);
}

extern "C" void kernel_launch(void* const* d_in, const int* in_sizes, int n_in,
                              void* d_out, int out_size, void* d_ws, size_t ws_size,
                              hipStream_t stream) {
    const float* x     = (const float*)d_in[0];
    const int*   src   = (const int*)d_in[1];
    const int*   dst   = (const int*)d_in[2];
    const float* W1l   = (const float*)d_in[3];
    const float* b1l   = (const float*)d_in[4];
    const float* W1r   = (const float*)d_in[5];
    const float* gamma = (const float*)d_in[6];
    const float* beta  = (const float*)d_in[7];
    const float* W2l   = (const float*)d_in[8];
    const float* b2l   = (const float*)d_in[9];
    const float* W2r   = (const float*)d_in[10];
    const float* Wc    = (const float*)d_in[11];
    const float* bc    = (const float*)d_in[12];
    const int E = in_sizes[1];

    float* ws    = (float*)d_ws;
    float* deg   = ws;                         // N (deg -> deg_inv in place)
    float* stats = ws + NN;                    // 256: sum, sumsq, scale, shift
    float* y1    = stats + 256;                // N*64
    float* xr    = y1 + (size_t)NN * 64;       // N*64
    float* agg1  = xr + (size_t)NN * 64;       // N*64 (becomes h)
    float* y2    = y1;                         // reuse y1 region: N*16
    float* hr2   = y1 + (size_t)NN * 16;       // N*16
    float* agg2  = y1 + (size_t)NN * 32;       // N*16
    float* out   = (float*)d_out;

    hipMemsetAsync(deg, 0, NN * sizeof(float), stream);
    hipMemsetAsync(stats, 0, 256 * sizeof(float), stream);
    hipMemsetAsync(agg1, 0, (size_t)NN * 64 * sizeof(float), stream);

    k_deg<<<(E + 255) / 256, 256, 0, stream>>>(dst, deg, E);
    k_deg_inv<<<(NN + 255) / 256, 256, 0, stream>>>(deg);

    dim3 g1((NN + 31) / 32, 2);
    k_gemm1<<<g1, 256, 0, stream>>>(x, W1l, W1r, y1, xr);

    k_scatter<64, 4><<<((E << 4) + 255) / 256, 256, 0, stream>>>(y1, src, dst, agg1, E);

    k_h_stats<<<(NN + 127) / 128, 256, 0, stream>>>(agg1, xr, b1l, deg, stats);
    k_bn_final<<<1, 64, 0, stream>>>(stats, gamma, beta);

    hipMemsetAsync(agg2, 0, (size_t)NN * 16 * sizeof(float), stream);
    k_gemm2<<<(NN + 63) / 64, 256, 0, stream>>>(agg1, W2l, W2r, stats, y2, hr2);

    k_scatter<16, 2><<<((E << 2) + 255) / 256, 256, 0, stream>>>(y2, src, dst, agg2, E);

    k_emb<<<(NN + 255) / 256, 256, 0, stream>>>(agg2, hr2, b2l, deg, Wc, bc, out);
}

// Round 4
// 576.856 us; speedup vs baseline: 3.3662x; 3.3662x over previous
//
#include <hip/hip_runtime.h>

#define NN 100000
#define NB ((NN + 255) / 256)   // 391 scan blocks
#define IND 128
#define HIDD 64

// ---------------- degree histogram (int) ----------------
__global__ void k_deg(const int* __restrict__ dst, int* __restrict__ deg, int E) {
    int i = blockIdx.x * 256 + threadIdx.x;
    if (i < E) atomicAdd(&deg[dst[i]], 1);
}

// ---------------- scan pass A: per-block exclusive scan + block sums -------------
__global__ __launch_bounds__(256) void k_scanA(const int* __restrict__ deg,
                                               int* __restrict__ rowptr,
                                               int* __restrict__ bsum) {
    const int tid = threadIdx.x;
    const int i = blockIdx.x * 256 + tid;
    int v = (i < NN) ? deg[i] : 0;
    const int lane = tid & 63, w = tid >> 6;
    int inc = v;
    #pragma unroll
    for (int d = 1; d < 64; d <<= 1) {
        int t = __shfl_up(inc, d, 64);
        if (lane >= d) inc += t;
    }
    __shared__ int wsum[4];
    if (lane == 63) wsum[w] = inc;
    __syncthreads();
    int wo = 0;
    for (int k = 0; k < w; ++k) wo += wsum[k];
    if (i < NN) rowptr[i] = wo + inc - v;          // exclusive, block-local
    if (tid == 255) bsum[blockIdx.x] = wo + inc;   // block total
}

// ---------------- scan pass B: scan the 391 block sums in-place ------------------
__global__ __launch_bounds__(512) void k_scanB(int* __restrict__ bsum,
                                               int* __restrict__ rowptr, int E) {
    const int tid = threadIdx.x;
    int v = (tid < NB) ? bsum[tid] : 0;
    const int lane = tid & 63, w = tid >> 6;
    int inc = v;
    #pragma unroll
    for (int d = 1; d < 64; d <<= 1) {
        int t = __shfl_up(inc, d, 64);
        if (lane >= d) inc += t;
    }
    __shared__ int wsum[8];
    if (lane == 63) wsum[w] = inc;
    __syncthreads();
    int wo = 0;
    for (int k = 0; k < w; ++k) wo += wsum[k];
    if (tid < NB) bsum[tid] = wo + inc - v;        // exclusive block offsets
    if (tid == 0) rowptr[NN] = E;
}

// ---------------- finish: rowptr += block offset; cursor; deg_inv ---------------
__global__ void k_finish(int* __restrict__ rowptr, const int* __restrict__ bsum,
                         const int* __restrict__ deg, int* __restrict__ cursor,
                         float* __restrict__ deg_inv) {
    int i = blockIdx.x * 256 + threadIdx.x;
    if (i < NN) {
        int rp = rowptr[i] + bsum[i >> 8];
        rowptr[i] = rp;
        cursor[i] = rp;
        deg_inv[i] = 1.0f / fmaxf((float)deg[i], 1.0f);
    }
}

// ---------------- CSR fill: eidx[rowptr[dst]+slot] = src -------------------------
__global__ void k_fill(const int* __restrict__ src, const int* __restrict__ dst,
                       int* __restrict__ cursor, int* __restrict__ eidx, int E) {
    int e = blockIdx.x * 256 + threadIdx.x;
    if (e < E) {
        int d = dst[e];
        int pos = atomicAdd(&cursor[d], 1);
        eidx[pos] = src[e];
    }
}

// ---------------- GEMM1: y1 = x@W1l.T, xr = x@W1r.T ------------------------------
__global__ __launch_bounds__(256) void k_gemm1(const float* __restrict__ x,
                                               const float* __restrict__ W1l,
                                               const float* __restrict__ W1r,
                                               float* __restrict__ y1,
                                               float* __restrict__ xr) {
    __shared__ float lw[IND][68];   // lw[k][j] = Wh[j][k]
    __shared__ float lx[32][132];
    const int tid = threadIdx.x;
    const float* Wh = (blockIdx.y == 0) ? W1l : W1r;
    float* out = (blockIdx.y == 0) ? y1 : xr;
    for (int idx = tid; idx < 64 * 128; idx += 256) {
        int j = idx >> 7, k = idx & 127;
        lw[k][j] = Wh[idx];
    }
    const int row0 = blockIdx.x * 32;
    for (int i = 0; i < 4; ++i) {
        int f4 = i * 256 + tid;
        int r  = f4 >> 5;
        int k4 = (f4 & 31) << 2;
        int grow = row0 + r;
        float4 v = make_float4(0.f, 0.f, 0.f, 0.f);
        if (grow < NN) v = *(const float4*)(x + (size_t)grow * IND + k4);
        *(float4*)(&lx[r][k4]) = v;
    }
    __syncthreads();
    const int cg = tid & 15;
    const int rl = tid >> 4;
    #pragma unroll
    for (int p = 0; p < 2; ++p) {
        int r = p * 16 + rl;
        int grow = row0 + r;
        float ax = 0.f, ay = 0.f, az = 0.f, aw = 0.f;
        #pragma unroll 8
        for (int k = 0; k < 128; ++k) {
            float xv = lx[r][k];
            float4 wv = *(const float4*)(&lw[k][cg << 2]);
            ax = fmaf(xv, wv.x, ax); ay = fmaf(xv, wv.y, ay);
            az = fmaf(xv, wv.z, az); aw = fmaf(xv, wv.w, aw);
        }
        if (grow < NN)
            *(float4*)(out + (size_t)grow * HIDD + (cg << 2)) = make_float4(ax, ay, az, aw);
    }
}

// ---------------- gather1: h = gather-mean(y1)*deg_inv + xr + b1l; BN stats ------
// one wave per node, lane = feature (64). xr is read from h[] (in-place update).
__global__ __launch_bounds__(256) void k_gather1(const float* __restrict__ y1,
        const int* __restrict__ rowptr, const int* __restrict__ eidx,
        const float* __restrict__ b1l,
        const float* __restrict__ deg_inv, float* __restrict__ h,
        float* __restrict__ stats) {
    const int tid = threadIdx.x;
    const int f = tid & 63, w = tid >> 6;
    const float bias = b1l[f];
    float a1 = 0.f, a2 = 0.f;
    for (int n = blockIdx.x * 4 + w; n < NN; n += gridDim.x * 4) {
        int beg = rowptr[n], end = rowptr[n + 1];
        float s0 = 0.f, s1 = 0.f;
        int j = beg;
        for (; j + 1 < end; j += 2) {
            int i0 = eidx[j], i1 = eidx[j + 1];
            s0 += y1[(size_t)i0 * 64 + f];
            s1 += y1[(size_t)i1 * 64 + f];
        }
        if (j < end) s0 += y1[(size_t)eidx[j] * 64 + f];
        size_t off = (size_t)n * 64 + f;
        float hv = fmaf(s0 + s1, deg_inv[n], h[off] + bias);   // h[off] holds xr
        h[off] = hv;
        a1 += hv; a2 = fmaf(hv, hv, a2);
    }
    __shared__ float sA[4][64], sB[4][64];
    sA[w][f] = a1; sB[w][f] = a2;
    __syncthreads();
    if (w == 0) {
        atomicAdd(&stats[f],      sA[0][f] + sA[1][f] + sA[2][f] + sA[3][f]);
        atomicAdd(&stats[64 + f], sB[0][f] + sB[1][f] + sB[2][f] + sB[3][f]);
    }
}

__global__ void k_bn_final(float* __restrict__ stats, const float* __restrict__ gamma,
                           const float* __restrict__ beta) {
    int f = threadIdx.x;
    float mu = stats[f] * (1.0f / NN);
    float var = stats[64 + f] * (1.0f / NN) - mu * mu;
    float sc = gamma[f] * rsqrtf(var + 1e-5f);
    stats[128 + f] = sc;
    stats[192 + f] = beta[f] - mu * sc;
}

// ---------------- GEMM2 (BN+ReLU fused): y2 = hbn@W2l.T, hr2 = hbn@W2r.T ---------
__global__ __launch_bounds__(256) void k_gemm2(const float* __restrict__ h,
        const float* __restrict__ W2l, const float* __restrict__ W2r,
        const float* __restrict__ stats,
        float* __restrict__ y2, float* __restrict__ hr2) {
    __shared__ float lh[64][68];
    __shared__ float lw[64][36];
    const int tid = threadIdx.x;
    for (int idx = tid; idx < 32 * 64; idx += 256) {
        int j = idx >> 6, k = idx & 63;
        lw[k][j] = (j < 16) ? W2l[idx] : W2r[idx - 1024];
    }
    const int row0 = blockIdx.x * 64;
    for (int i = 0; i < 4; ++i) {
        int f4 = i * 256 + tid;
        int r = f4 >> 4;
        int k4 = (f4 & 15) << 2;
        int grow = row0 + r;
        float4 v = make_float4(0.f, 0.f, 0.f, 0.f);
        if (grow < NN) v = *(const float4*)(h + (size_t)grow * 64 + k4);
        float4 sc = *(const float4*)(stats + 128 + k4);
        float4 sh = *(const float4*)(stats + 192 + k4);
        float4 o;
        o.x = fmaxf(fmaf(v.x, sc.x, sh.x), 0.f);
        o.y = fmaxf(fmaf(v.y, sc.y, sh.y), 0.f);
        o.z = fmaxf(fmaf(v.z, sc.z, sh.z), 0.f);
        o.w = fmaxf(fmaf(v.w, sc.w, sh.w), 0.f);
        *(float4*)(&lh[r][k4]) = o;
    }
    __syncthreads();
    const int cg = tid & 7;
    const int rl = tid >> 3;
    #pragma unroll
    for (int p = 0; p < 2; ++p) {
        int r = p * 32 + rl;
        int grow = row0 + r;
        float ax = 0.f, ay = 0.f, az = 0.f, aw = 0.f;
        #pragma unroll
        for (int k = 0; k < 64; ++k) {
            float hv = lh[r][k];
            float4 wv = *(const float4*)(&lw[k][cg << 2]);
            ax = fmaf(hv, wv.x, ax); ay = fmaf(hv, wv.y, ay);
            az = fmaf(hv, wv.z, az); aw = fmaf(hv, wv.w, aw);
        }
        if (grow < NN) {
            int c = cg << 2;
            if (c < 16) *(float4*)(y2  + (size_t)grow * 16 + c)        = make_float4(ax, ay, az, aw);
            else        *(float4*)(hr2 + (size_t)grow * 16 + (c - 16)) = make_float4(ax, ay, az, aw);
        }
    }
}

// ---------------- gather2 + epilogue: emb + logits straight to d_out -------------
// 16 lanes per node (4 nodes per wave)
__global__ __launch_bounds__(256) void k_gather2(const float* __restrict__ y2,
        const int* __restrict__ rowptr, const int* __restrict__ eidx,
        const float* __restrict__ hr2, const float* __restrict__ b2l,
        const float* __restrict__ deg_inv, const float* __restrict__ Wc,
        const float* __restrict__ bc, float* __restrict__ out) {
    const int tid = threadIdx.x;
    const int f = tid & 15, g = tid >> 4;   // 16 node-groups per block
    const float wc0 = Wc[f], wc1 = Wc[16 + f];
    const float bias = b2l[f];
    for (int n = blockIdx.x * 16 + g; n < NN; n += gridDim.x * 16) {
        int beg = rowptr[n], end = rowptr[n + 1];
        float s0 = 0.f, s1 = 0.f;
        int j = beg;
        for (; j + 1 < end; j += 2) {
            int i0 = eidx[j], i1 = eidx[j + 1];
            s0 += y2[(size_t)i0 * 16 + f];
            s1 += y2[(size_t)i1 * 16 + f];
        }
        if (j < end) s0 += y2[(size_t)eidx[j] * 16 + f];
        float e = fmaf(s0 + s1, deg_inv[n], hr2[(size_t)n * 16 + f] + bias);
        out[(size_t)(2 * NN) + (size_t)n * 16 + f] = e;
        float l0 = e * wc0, l1 = e * wc1;
        #pragma unroll
        for (int m = 1; m < 16; m <<= 1) {
            l0 += __shfl_xor(l0, m, 64);
            l1 += __shfl_xor(l1, m, 64);
        }
        if (f == 0) {
            out[(size_t)n * 2]     = l0 + bc[0];
            out[(size_t)n * 2 + 1] = l1 + bc[1];
        }
    }
}

extern "C" void kernel_launch(void* const* d_in, const int* in_sizes, int n_in,
                              void* d_out, int out_size, void* d_ws, size_t ws_size,
                              hipStream_t stream) {
    const float* x     = (const float*)d_in[0];
    const int*   src   = (const int*)d_in[1];
    const int*   dst   = (const int*)d_in[2];
    const float* W1l   = (const float*)d_in[3];
    const float* b1l   = (const float*)d_in[4];
    const float* W1r   = (const float*)d_in[5];
    const float* gamma = (const float*)d_in[6];
    const float* beta  = (const float*)d_in[7];
    const float* W2l   = (const float*)d_in[8];
    const float* b2l   = (const float*)d_in[9];
    const float* W2r   = (const float*)d_in[10];
    const float* Wc    = (const float*)d_in[11];
    const float* bc    = (const float*)d_in[12];
    const int E = in_sizes[1];

    // ---- workspace layout (floats), all region starts 16B-aligned ---------------
    // rowptr[NN+1] | deg_inv[NN] | stats[256] | eidx[E] | y1[NN*64] | h[NN*64]
    // overlays: deg_i,cursor live in y1 region (dead before gemm1 writes y1);
    //           bsum lives in eidx region (dead before fill writes eidx);
    //           xr IS h (gemm1 writes it, gather1 updates in place);
    //           y2/hr2 reuse y1 region after gather1.
    float* ws      = (float*)d_ws;
    int*   rowptr  = (int*)ws;                        // 100352 slots
    float* deg_inv = ws + 100352;                     // 100352 slots
    float* stats   = ws + 200704;                     // 256
    int*   eidx    = (int*)(ws + 200960);             // E
    float* y1      = ws + 200960 + (size_t)E;         // NN*64
    float* h       = y1 + (size_t)NN * 64;            // NN*64
    int*   deg_i   = (int*)y1;
    int*   cursor  = (int*)y1 + 102400;               // disjoint from deg_i, 16B-aligned
    int*   bsum    = eidx;
    float* xr      = h;
    float* y2      = y1;
    float* hr2     = y1 + (size_t)NN * 16;
    float* out     = (float*)d_out;

    hipMemsetAsync(deg_i, 0, NN * sizeof(int), stream);
    hipMemsetAsync(stats, 0, 256 * sizeof(float), stream);

    k_deg<<<(E + 255) / 256, 256, 0, stream>>>(dst, deg_i, E);
    k_scanA<<<NB, 256, 0, stream>>>(deg_i, rowptr, bsum);
    k_scanB<<<1, 512, 0, stream>>>(bsum, rowptr, E);
    k_finish<<<NB, 256, 0, stream>>>(rowptr, bsum, deg_i, cursor, deg_inv);
    k_fill<<<(E + 255) / 256, 256, 0, stream>>>(src, dst, cursor, eidx, E);

    dim3 g1((NN + 31) / 32, 2);
    k_gemm1<<<g1, 256, 0, stream>>>(x, W1l, W1r, y1, xr);

    k_gather1<<<2048, 256, 0, stream>>>(y1, rowptr, eidx, b1l, deg_inv, h, stats);
    k_bn_final<<<1, 64, 0, stream>>>(stats, gamma, beta);

    k_gemm2<<<(NN + 63) / 64, 256, 0, stream>>>(h, W2l, W2r, stats, y2, hr2);

    k_gather2<<<1024, 256, 0, stream>>>(y2, rowptr, eidx, hr2, b2l, deg_inv, Wc, bc, out);
}

// Round 5
// 473.833 us; speedup vs baseline: 4.0981x; 1.2174x over previous
//
#include <hip/hip_runtime.h>

#define NN 100000
#define NB ((NN + 255) / 256)   // 391 scan blocks

// ================= shared GEMM body: out[32 rows x 64 cols] = x(128) @ W.T ======
// K tiled at 64 -> LDS 26 KB, 6 blocks/CU. Block = 256 thr.
__device__ __forceinline__ void gemm32x64(const float* __restrict__ x,
        const float* __restrict__ W, float* __restrict__ out,
        int rb, int tid, float (*lw)[68], float (*lx)[68]) {
    const int row0 = rb * 32;
    const int cg = tid & 15, rl = tid >> 4;
    float acc[2][4] = {{0.f,0.f,0.f,0.f},{0.f,0.f,0.f,0.f}};
    for (int kt = 0; kt < 2; ++kt) {
        if (kt) __syncthreads();
        for (int idx = tid; idx < 4096; idx += 256) {   // lw[k][j] = W[j][kt*64+k]
            int j = idx >> 6, k = idx & 63;
            lw[k][j] = W[j * 128 + kt * 64 + k];
        }
        #pragma unroll
        for (int i = 0; i < 2; ++i) {                    // lx[r][k] = x[row0+r][kt*64+k]
            int f4 = i * 256 + tid;
            int r = f4 >> 4, k4 = (f4 & 15) << 2;
            int grow = row0 + r;
            float4 vv = make_float4(0.f, 0.f, 0.f, 0.f);
            if (grow < NN) vv = *(const float4*)(x + (size_t)grow * 128 + kt * 64 + k4);
            *(float4*)(&lx[r][k4]) = vv;
        }
        __syncthreads();
        #pragma unroll
        for (int p = 0; p < 2; ++p) {
            int r = p * 16 + rl;
            #pragma unroll 8
            for (int k = 0; k < 64; ++k) {
                float xv = lx[r][k];
                float4 wv = *(const float4*)(&lw[k][cg << 2]);
                acc[p][0] = fmaf(xv, wv.x, acc[p][0]);
                acc[p][1] = fmaf(xv, wv.y, acc[p][1]);
                acc[p][2] = fmaf(xv, wv.z, acc[p][2]);
                acc[p][3] = fmaf(xv, wv.w, acc[p][3]);
            }
        }
    }
    #pragma unroll
    for (int p = 0; p < 2; ++p) {
        int grow = row0 + p * 16 + rl;
        if (grow < NN)
            *(float4*)(out + (size_t)grow * 64 + (cg << 2)) =
                make_float4(acc[p][0], acc[p][1], acc[p][2], acc[p][3]);
    }
}

// ================= fusedA: deg histogram + gemm1(y1 = x@W1l.T) ==================
// 16-block groups: v<8 -> deg role (512 edges each), v>=8 -> gemm role.
__global__ __launch_bounds__(256) void k_fusedA(const float* __restrict__ x,
        const float* __restrict__ W1l, const int* __restrict__ dst,
        int* __restrict__ deg, float* __restrict__ y1, int E) {
    __shared__ float lw[64][68];
    __shared__ float lx[32][68];
    const int tid = threadIdx.x;
    const int u = blockIdx.x >> 4, v = blockIdx.x & 15;
    if (v < 8) {
        const int base = (u * 8 + v) * 512;
        #pragma unroll
        for (int i = 0; i < 2; ++i) {
            int e = base + i * 256 + tid;
            if (e < E) atomicAdd(&deg[dst[e]], 1);
        }
        return;
    }
    const int rb = u * 8 + (v - 8);
    if (rb >= 3125) return;
    gemm32x64(x, W1l, y1, rb, tid, lw, lx);
}

// ================= fusedB: XCD-segmented CSR fill + gemm1(xr = x@W1r.T -> h) ====
// fill role: block with v = seg handles only dst in [seg*12500, +12500) so all
// eidx writes land in one contiguous region owned by one XCD's L2 (no
// cross-XCD false sharing). chunk = u covers 4096 edges.
__global__ __launch_bounds__(256) void k_fusedB(const float* __restrict__ x,
        const float* __restrict__ W1r, const int* __restrict__ src,
        const int* __restrict__ dst, int* __restrict__ cursor,
        int* __restrict__ eidx, float* __restrict__ h, int E) {
    __shared__ float lw[64][68];
    __shared__ float lx[32][68];
    const int tid = threadIdx.x;
    const int u = blockIdx.x >> 4, v = blockIdx.x & 15;
    if (v < 8) {
        const int base = u * 4096;
        const int lo = v * 12500, hi = lo + 12500;
        #pragma unroll 4
        for (int i = 0; i < 16; ++i) {
            int e = base + i * 256 + tid;
            if (e < E) {
                int d = dst[e];
                if (d >= lo && d < hi) {
                    int pos = atomicAdd(&cursor[d], 1);
                    eidx[pos] = src[e];
                }
            }
        }
        return;
    }
    const int rb = u * 8 + (v - 8);
    if (rb >= 3125) return;
    gemm32x64(x, W1r, h, rb, tid, lw, lx);
}

// ---------------- scan pass A: per-block exclusive scan + block sums -------------
__global__ __launch_bounds__(256) void k_scanA(const int* __restrict__ deg,
                                               int* __restrict__ rowptr,
                                               int* __restrict__ bsum) {
    const int tid = threadIdx.x;
    const int i = blockIdx.x * 256 + tid;
    int v = (i < NN) ? deg[i] : 0;
    const int lane = tid & 63, w = tid >> 6;
    int inc = v;
    #pragma unroll
    for (int d = 1; d < 64; d <<= 1) {
        int t = __shfl_up(inc, d, 64);
        if (lane >= d) inc += t;
    }
    __shared__ int wsum[4];
    if (lane == 63) wsum[w] = inc;
    __syncthreads();
    int wo = 0;
    for (int k = 0; k < w; ++k) wo += wsum[k];
    if (i < NN) rowptr[i] = wo + inc - v;
    if (tid == 255) bsum[blockIdx.x] = wo + inc;
}

// ---------------- scan pass B: scan the 391 block sums in-place ------------------
__global__ __launch_bounds__(512) void k_scanB(int* __restrict__ bsum,
                                               int* __restrict__ rowptr, int E) {
    const int tid = threadIdx.x;
    int v = (tid < NB) ? bsum[tid] : 0;
    const int lane = tid & 63, w = tid >> 6;
    int inc = v;
    #pragma unroll
    for (int d = 1; d < 64; d <<= 1) {
        int t = __shfl_up(inc, d, 64);
        if (lane >= d) inc += t;
    }
    __shared__ int wsum[8];
    if (lane == 63) wsum[w] = inc;
    __syncthreads();
    int wo = 0;
    for (int k = 0; k < w; ++k) wo += wsum[k];
    if (tid < NB) bsum[tid] = wo + inc - v;
    if (tid == 0) rowptr[NN] = E;
}

// ---------------- finish: rowptr += block offset; cursor; deg_inv ---------------
__global__ void k_finish(int* __restrict__ rowptr, const int* __restrict__ bsum,
                         const int* __restrict__ deg, int* __restrict__ cursor,
                         float* __restrict__ deg_inv) {
    int i = blockIdx.x * 256 + threadIdx.x;
    if (i < NN) {
        int rp = rowptr[i] + bsum[i >> 8];
        rowptr[i] = rp;
        cursor[i] = rp;
        deg_inv[i] = 1.0f / fmaxf((float)deg[i], 1.0f);
    }
}

// ---------------- gather1: h = mean(y1[nbrs])*deg_inv + xr + b1l; BN stats -------
// one wave per node, lane = feature, ILP-4 gather streams
__global__ __launch_bounds__(256) void k_gather1(const float* __restrict__ y1,
        const int* __restrict__ rowptr, const int* __restrict__ eidx,
        const float* __restrict__ b1l,
        const float* __restrict__ deg_inv, float* __restrict__ h,
        float* __restrict__ stats) {
    const int tid = threadIdx.x;
    const int f = tid & 63, w = tid >> 6;
    const float bias = b1l[f];
    float a1 = 0.f, a2 = 0.f;
    for (int n = blockIdx.x * 4 + w; n < NN; n += gridDim.x * 4) {
        int beg = rowptr[n], end = rowptr[n + 1];
        float s0 = 0.f, s1 = 0.f, s2 = 0.f, s3 = 0.f;
        int j = beg;
        for (; j + 3 < end; j += 4) {
            int i0 = eidx[j], i1 = eidx[j + 1], i2 = eidx[j + 2], i3 = eidx[j + 3];
            s0 += y1[(size_t)i0 * 64 + f];
            s1 += y1[(size_t)i1 * 64 + f];
            s2 += y1[(size_t)i2 * 64 + f];
            s3 += y1[(size_t)i3 * 64 + f];
        }
        for (; j < end; ++j) s0 += y1[(size_t)eidx[j] * 64 + f];
        size_t off = (size_t)n * 64 + f;
        float hv = fmaf((s0 + s1) + (s2 + s3), deg_inv[n], h[off] + bias); // h holds xr
        h[off] = hv;
        a1 += hv; a2 = fmaf(hv, hv, a2);
    }
    __shared__ float sA[4][64], sB[4][64];
    sA[w][f] = a1; sB[w][f] = a2;
    __syncthreads();
    if (w == 0) {
        atomicAdd(&stats[f],      sA[0][f] + sA[1][f] + sA[2][f] + sA[3][f]);
        atomicAdd(&stats[64 + f], sB[0][f] + sB[1][f] + sB[2][f] + sB[3][f]);
    }
}

__global__ void k_bn_final(float* __restrict__ stats, const float* __restrict__ gamma,
                           const float* __restrict__ beta) {
    int f = threadIdx.x;
    float mu = stats[f] * (1.0f / NN);
    float var = stats[64 + f] * (1.0f / NN) - mu * mu;
    float sc = gamma[f] * rsqrtf(var + 1e-5f);
    stats[128 + f] = sc;
    stats[192 + f] = beta[f] - mu * sc;
}

// ---------------- GEMM2 (BN+ReLU fused): y2 = hbn@W2l.T, hr2 = hbn@W2r.T ---------
__global__ __launch_bounds__(256) void k_gemm2(const float* __restrict__ h,
        const float* __restrict__ W2l, const float* __restrict__ W2r,
        const float* __restrict__ stats,
        float* __restrict__ y2, float* __restrict__ hr2) {
    __shared__ float lh[64][68];
    __shared__ float lw[64][36];
    const int tid = threadIdx.x;
    for (int idx = tid; idx < 32 * 64; idx += 256) {
        int j = idx >> 6, k = idx & 63;
        lw[k][j] = (j < 16) ? W2l[idx] : W2r[idx - 1024];
    }
    const int row0 = blockIdx.x * 64;
    for (int i = 0; i < 4; ++i) {
        int f4 = i * 256 + tid;
        int r = f4 >> 4;
        int k4 = (f4 & 15) << 2;
        int grow = row0 + r;
        float4 v = make_float4(0.f, 0.f, 0.f, 0.f);
        if (grow < NN) v = *(const float4*)(h + (size_t)grow * 64 + k4);
        float4 sc = *(const float4*)(stats + 128 + k4);
        float4 sh = *(const float4*)(stats + 192 + k4);
        float4 o;
        o.x = fmaxf(fmaf(v.x, sc.x, sh.x), 0.f);
        o.y = fmaxf(fmaf(v.y, sc.y, sh.y), 0.f);
        o.z = fmaxf(fmaf(v.z, sc.z, sh.z), 0.f);
        o.w = fmaxf(fmaf(v.w, sc.w, sh.w), 0.f);
        *(float4*)(&lh[r][k4]) = o;
    }
    __syncthreads();
    const int cg = tid & 7;
    const int rl = tid >> 3;
    #pragma unroll
    for (int p = 0; p < 2; ++p) {
        int r = p * 32 + rl;
        int grow = row0 + r;
        float ax = 0.f, ay = 0.f, az = 0.f, aw = 0.f;
        #pragma unroll
        for (int k = 0; k < 64; ++k) {
            float hv = lh[r][k];
            float4 wv = *(const float4*)(&lw[k][cg << 2]);
            ax = fmaf(hv, wv.x, ax); ay = fmaf(hv, wv.y, ay);
            az = fmaf(hv, wv.z, az); aw = fmaf(hv, wv.w, aw);
        }
        if (grow < NN) {
            int c = cg << 2;
            if (c < 16) *(float4*)(y2  + (size_t)grow * 16 + c)        = make_float4(ax, ay, az, aw);
            else        *(float4*)(hr2 + (size_t)grow * 16 + (c - 16)) = make_float4(ax, ay, az, aw);
        }
    }
}

// ---------------- gather2 + epilogue: emb + logits straight to d_out -------------
// 16 lanes per node (4 nodes per wave), ILP-4
__global__ __launch_bounds__(256) void k_gather2(const float* __restrict__ y2,
        const int* __restrict__ rowptr, const int* __restrict__ eidx,
        const float* __restrict__ hr2, const float* __restrict__ b2l,
        const float* __restrict__ deg_inv, const float* __restrict__ Wc,
        const float* __restrict__ bc, float* __restrict__ out) {
    const int tid = threadIdx.x;
    const int f = tid & 15, g = tid >> 4;
    const float wc0 = Wc[f], wc1 = Wc[16 + f];
    const float bias = b2l[f];
    for (int n = blockIdx.x * 16 + g; n < NN; n += gridDim.x * 16) {
        int beg = rowptr[n], end = rowptr[n + 1];
        float s0 = 0.f, s1 = 0.f, s2 = 0.f, s3 = 0.f;
        int j = beg;
        for (; j + 3 < end; j += 4) {
            int i0 = eidx[j], i1 = eidx[j + 1], i2 = eidx[j + 2], i3 = eidx[j + 3];
            s0 += y2[(size_t)i0 * 16 + f];
            s1 += y2[(size_t)i1 * 16 + f];
            s2 += y2[(size_t)i2 * 16 + f];
            s3 += y2[(size_t)i3 * 16 + f];
        }
        for (; j < end; ++j) s0 += y2[(size_t)eidx[j] * 16 + f];
        float e = fmaf((s0 + s1) + (s2 + s3), deg_inv[n], hr2[(size_t)n * 16 + f] + bias);
        out[(size_t)(2 * NN) + (size_t)n * 16 + f] = e;
        float l0 = e * wc0, l1 = e * wc1;
        #pragma unroll
        for (int m = 1; m < 16; m <<= 1) {
            l0 += __shfl_xor(l0, m, 64);
            l1 += __shfl_xor(l1, m, 64);
        }
        if (f == 0) {
            out[(size_t)n * 2]     = l0 + bc[0];
            out[(size_t)n * 2 + 1] = l1 + bc[1];
        }
    }
}

extern "C" void kernel_launch(void* const* d_in, const int* in_sizes, int n_in,
                              void* d_out, int out_size, void* d_ws, size_t ws_size,
                              hipStream_t stream) {
    const float* x     = (const float*)d_in[0];
    const int*   src   = (const int*)d_in[1];
    const int*   dst   = (const int*)d_in[2];
    const float* W1l   = (const float*)d_in[3];
    const float* b1l   = (const float*)d_in[4];
    const float* W1r   = (const float*)d_in[5];
    const float* gamma = (const float*)d_in[6];
    const float* beta  = (const float*)d_in[7];
    const float* W2l   = (const float*)d_in[8];
    const float* b2l   = (const float*)d_in[9];
    const float* W2r   = (const float*)d_in[10];
    const float* Wc    = (const float*)d_in[11];
    const float* bc    = (const float*)d_in[12];
    const int E = in_sizes[1];

    // ---- workspace layout (floats) ----------------------------------------------
    // rowptr[100352] | deg_inv[100352] | stats[256] | deg_i[100352] | cursor[100352]
    // | eidx[E] | y1[NN*64] | h[NN*64]   (~59.2 MB)
    // overlays: bsum in eidx region (dead before fill); y2/hr2 reuse y1 after
    // gather1; xr IS h (fusedB writes it, gather1 updates in place).
    float* ws      = (float*)d_ws;
    int*   rowptr  = (int*)ws;
    float* deg_inv = ws + 100352;
    float* stats   = ws + 200704;
    int*   deg_i   = (int*)(ws + 200960);
    int*   cursor  = (int*)(ws + 301312);
    int*   eidx    = (int*)(ws + 401664);
    float* y1      = ws + 401664 + (size_t)E;
    float* h       = y1 + (size_t)NN * 64;
    int*   bsum    = eidx;
    float* y2      = y1;
    float* hr2     = y1 + (size_t)NN * 16;
    float* out     = (float*)d_out;

    hipMemsetAsync(deg_i, 0, NN * sizeof(int), stream);
    hipMemsetAsync(stats, 0, 256 * sizeof(float), stream);

    // fusedA: deg (u<391 chunks x 8) + gemm1 y1 (3125 tiles). T = 16*391 = 6256.
    k_fusedA<<<6256, 256, 0, stream>>>(x, W1l, dst, deg_i, y1, E);

    k_scanA<<<NB, 256, 0, stream>>>(deg_i, rowptr, bsum);
    k_scanB<<<1, 512, 0, stream>>>(bsum, rowptr, E);
    k_finish<<<NB, 256, 0, stream>>>(rowptr, bsum, deg_i, cursor, deg_inv);

    // fusedB: XCD-segmented fill + gemm1 xr->h. T = 16*391 = 6256.
    k_fusedB<<<6256, 256, 0, stream>>>(x, W1r, src, dst, cursor, eidx, h, E);

    k_gather1<<<4096, 256, 0, stream>>>(y1, rowptr, eidx, b1l, deg_inv, h, stats);
    k_bn_final<<<1, 64, 0, stream>>>(stats, gamma, beta);

    k_gemm2<<<(NN + 63) / 64, 256, 0, stream>>>(h, W2l, W2r, stats, y2, hr2);

    k_gather2<<<2048, 256, 0, stream>>>(y2, rowptr, eidx, hr2, b2l, deg_inv, Wc, bc, out);
}

// Round 7
// 448.275 us; speedup vs baseline: 4.3318x; 1.0570x over previous
//
#include <hip/hip_runtime.h>

#define NN 100000
#define NB ((NN + 255) / 256)   // 391 scan blocks

// bf16 helpers (RNE pack)
__device__ __forceinline__ unsigned short f2bf(float x) {
    unsigned u = __float_as_uint(x);
    u += 0x7fff + ((u >> 16) & 1);
    return (unsigned short)(u >> 16);
}
__device__ __forceinline__ float bf2f(unsigned short h) {
    return __uint_as_float(((unsigned)h) << 16);
}

// ================= shared GEMM body: out[32 rows x 64 cols] = x(128) @ W.T ======
// K tiled at 64 -> LDS 26 KB. Block = 256 thr. BF16 selects packed output.
template<bool BF16>
__device__ __forceinline__ void gemm32x64(const float* __restrict__ x,
        const float* __restrict__ W, void* __restrict__ out,
        int rb, int tid, float (*lw)[68], float (*lx)[68]) {
    const int row0 = rb * 32;
    const int cg = tid & 15, rl = tid >> 4;
    float acc[2][4] = {{0.f,0.f,0.f,0.f},{0.f,0.f,0.f,0.f}};
    for (int kt = 0; kt < 2; ++kt) {
        if (kt) __syncthreads();
        for (int idx = tid; idx < 4096; idx += 256) {   // lw[k][j] = W[j][kt*64+k]
            int j = idx >> 6, k = idx & 63;
            lw[k][j] = W[j * 128 + kt * 64 + k];
        }
        #pragma unroll
        for (int i = 0; i < 2; ++i) {                    // lx[r][k] = x[row0+r][kt*64+k]
            int f4 = i * 256 + tid;
            int r = f4 >> 4, k4 = (f4 & 15) << 2;
            int grow = row0 + r;
            float4 vv = make_float4(0.f, 0.f, 0.f, 0.f);
            if (grow < NN) vv = *(const float4*)(x + (size_t)grow * 128 + kt * 64 + k4);
            *(float4*)(&lx[r][k4]) = vv;
        }
        __syncthreads();
        #pragma unroll
        for (int p = 0; p < 2; ++p) {
            int r = p * 16 + rl;
            #pragma unroll 8
            for (int k = 0; k < 64; ++k) {
                float xv = lx[r][k];
                float4 wv = *(const float4*)(&lw[k][cg << 2]);
                acc[p][0] = fmaf(xv, wv.x, acc[p][0]);
                acc[p][1] = fmaf(xv, wv.y, acc[p][1]);
                acc[p][2] = fmaf(xv, wv.z, acc[p][2]);
                acc[p][3] = fmaf(xv, wv.w, acc[p][3]);
            }
        }
    }
    #pragma unroll
    for (int p = 0; p < 2; ++p) {
        int grow = row0 + p * 16 + rl;
        if (grow < NN) {
            if (BF16) {
                ushort4 o;
                o.x = f2bf(acc[p][0]); o.y = f2bf(acc[p][1]);
                o.z = f2bf(acc[p][2]); o.w = f2bf(acc[p][3]);
                *(ushort4*)((unsigned short*)out + (size_t)grow * 64 + (cg << 2)) = o;
            } else {
                *(float4*)((float*)out + (size_t)grow * 64 + (cg << 2)) =
                    make_float4(acc[p][0], acc[p][1], acc[p][2], acc[p][3]);
            }
        }
    }
}

// ================= fusedA: deg histogram + gemm1(y1 = bf16(x@W1l.T)) ============
__global__ __launch_bounds__(256) void k_fusedA(const float* __restrict__ x,
        const float* __restrict__ W1l, const int* __restrict__ dst,
        int* __restrict__ deg, unsigned short* __restrict__ y1, int E) {
    __shared__ float lw[64][68];
    __shared__ float lx[32][68];
    const int tid = threadIdx.x;
    const int u = blockIdx.x >> 4, v = blockIdx.x & 15;
    if (v < 8) {
        const int base = (u * 8 + v) * 512;
        #pragma unroll
        for (int i = 0; i < 2; ++i) {
            int e = base + i * 256 + tid;
            if (e < E) atomicAdd(&deg[dst[e]], 1);
        }
        return;
    }
    const int rb = u * 8 + (v - 8);
    if (rb >= 3125) return;
    gemm32x64<true>(x, W1l, y1, rb, tid, lw, lx);
}

// ================= fusedB: XCD-segmented CSR fill + gemm1(xr = x@W1r.T -> h) ====
__global__ __launch_bounds__(256) void k_fusedB(const float* __restrict__ x,
        const float* __restrict__ W1r, const int* __restrict__ src,
        const int* __restrict__ dst, int* __restrict__ cursor,
        int* __restrict__ eidx, float* __restrict__ h, int E) {
    __shared__ float lw[64][68];
    __shared__ float lx[32][68];
    const int tid = threadIdx.x;
    const int u = blockIdx.x >> 4, v = blockIdx.x & 15;
    if (v < 8) {
        const int base = u * 4096;
        const int lo = v * 12500, hi = lo + 12500;
        #pragma unroll 4
        for (int i = 0; i < 16; ++i) {
            int e = base + i * 256 + tid;
            if (e < E) {
                int d = dst[e];
                if (d >= lo && d < hi) {
                    int pos = atomicAdd(&cursor[d], 1);
                    eidx[pos] = src[e];
                }
            }
        }
        return;
    }
    const int rb = u * 8 + (v - 8);
    if (rb >= 3125) return;
    gemm32x64<false>(x, W1r, h, rb, tid, lw, lx);
}

// ---------------- scan pass A ----------------------------------------------------
__global__ __launch_bounds__(256) void k_scanA(const int* __restrict__ deg,
                                               int* __restrict__ rowptr,
                                               int* __restrict__ bsum) {
    const int tid = threadIdx.x;
    const int i = blockIdx.x * 256 + tid;
    int v = (i < NN) ? deg[i] : 0;
    const int lane = tid & 63, w = tid >> 6;
    int inc = v;
    #pragma unroll
    for (int d = 1; d < 64; d <<= 1) {
        int t = __shfl_up(inc, d, 64);
        if (lane >= d) inc += t;
    }
    __shared__ int wsum[4];
    if (lane == 63) wsum[w] = inc;
    __syncthreads();
    int wo = 0;
    for (int k = 0; k < w; ++k) wo += wsum[k];
    if (i < NN) rowptr[i] = wo + inc - v;
    if (tid == 255) bsum[blockIdx.x] = wo + inc;
}

// ---------------- scan pass B ----------------------------------------------------
__global__ __launch_bounds__(512) void k_scanB(int* __restrict__ bsum,
                                               int* __restrict__ rowptr, int E) {
    const int tid = threadIdx.x;
    int v = (tid < NB) ? bsum[tid] : 0;
    const int lane = tid & 63, w = tid >> 6;
    int inc = v;
    #pragma unroll
    for (int d = 1; d < 64; d <<= 1) {
        int t = __shfl_up(inc, d, 64);
        if (lane >= d) inc += t;
    }
    __shared__ int wsum[8];
    if (lane == 63) wsum[w] = inc;
    __syncthreads();
    int wo = 0;
    for (int k = 0; k < w; ++k) wo += wsum[k];
    if (tid < NB) bsum[tid] = wo + inc - v;
    if (tid == 0) rowptr[NN] = E;
}

// ---------------- finish ---------------------------------------------------------
__global__ void k_finish(int* __restrict__ rowptr, const int* __restrict__ bsum,
                         const int* __restrict__ deg, int* __restrict__ cursor,
                         float* __restrict__ deg_inv) {
    int i = blockIdx.x * 256 + threadIdx.x;
    if (i < NN) {
        int rp = rowptr[i] + bsum[i >> 8];
        rowptr[i] = rp;
        cursor[i] = rp;
        deg_inv[i] = 1.0f / fmaxf((float)deg[i], 1.0f);
    }
}

// ---------------- gather1: h = mean(bf16 y1[nbrs])*deg_inv + xr + b1l; BN stats --
__global__ __launch_bounds__(256) void k_gather1(const unsigned short* __restrict__ y1,
        const int* __restrict__ rowptr, const int* __restrict__ eidx,
        const float* __restrict__ b1l,
        const float* __restrict__ deg_inv, float* __restrict__ h,
        float* __restrict__ stats) {
    const int tid = threadIdx.x;
    const int f = tid & 63, w = tid >> 6;
    const float bias = b1l[f];
    float a1 = 0.f, a2 = 0.f;
    for (int n = blockIdx.x * 4 + w; n < NN; n += gridDim.x * 4) {
        int beg = rowptr[n], end = rowptr[n + 1];
        float s0 = 0.f, s1 = 0.f, s2 = 0.f, s3 = 0.f;
        int j = beg;
        for (; j + 3 < end; j += 4) {
            int i0 = eidx[j], i1 = eidx[j + 1], i2 = eidx[j + 2], i3 = eidx[j + 3];
            s0 += bf2f(y1[(size_t)i0 * 64 + f]);
            s1 += bf2f(y1[(size_t)i1 * 64 + f]);
            s2 += bf2f(y1[(size_t)i2 * 64 + f]);
            s3 += bf2f(y1[(size_t)i3 * 64 + f]);
        }
        for (; j < end; ++j) s0 += bf2f(y1[(size_t)eidx[j] * 64 + f]);
        size_t off = (size_t)n * 64 + f;
        float hv = fmaf((s0 + s1) + (s2 + s3), deg_inv[n], h[off] + bias); // h holds xr
        h[off] = hv;
        a1 += hv; a2 = fmaf(hv, hv, a2);
    }
    __shared__ float sA[4][64], sB[4][64];
    sA[w][f] = a1; sB[w][f] = a2;
    __syncthreads();
    if (w == 0) {
        atomicAdd(&stats[f],      sA[0][f] + sA[1][f] + sA[2][f] + sA[3][f]);
        atomicAdd(&stats[64 + f], sB[0][f] + sB[1][f] + sB[2][f] + sB[3][f]);
    }
}

// ---------------- GEMM2 (BN finalize + BN+ReLU fused): y2(bf16), hr2(fp32) -------
__global__ __launch_bounds__(256) void k_gemm2(const float* __restrict__ h,
        const float* __restrict__ W2l, const float* __restrict__ W2r,
        const float* __restrict__ stats, const float* __restrict__ gamma,
        const float* __restrict__ beta,
        unsigned short* __restrict__ y2, float* __restrict__ hr2) {
    __shared__ float lh[64][68];
    __shared__ float lw[64][36];
    __shared__ float lsc[64], lsh[64];
    const int tid = threadIdx.x;
    if (tid < 64) {   // BN finalize (redundant per block, cheap)
        float mu = stats[tid] * (1.0f / NN);
        float var = stats[64 + tid] * (1.0f / NN) - mu * mu;
        float sc = gamma[tid] * rsqrtf(var + 1e-5f);
        lsc[tid] = sc;
        lsh[tid] = beta[tid] - mu * sc;
    }
    for (int idx = tid; idx < 32 * 64; idx += 256) {
        int j = idx >> 6, k = idx & 63;
        lw[k][j] = (j < 16) ? W2l[idx] : W2r[idx - 1024];
    }
    __syncthreads();
    const int row0 = blockIdx.x * 64;
    for (int i = 0; i < 4; ++i) {
        int f4 = i * 256 + tid;
        int r = f4 >> 4;
        int k4 = (f4 & 15) << 2;
        int grow = row0 + r;
        float4 v = make_float4(0.f, 0.f, 0.f, 0.f);
        if (grow < NN) v = *(const float4*)(h + (size_t)grow * 64 + k4);
        float4 sc = *(const float4*)(&lsc[k4]);
        float4 sh = *(const float4*)(&lsh[k4]);
        float4 o;
        o.x = fmaxf(fmaf(v.x, sc.x, sh.x), 0.f);
        o.y = fmaxf(fmaf(v.y, sc.y, sh.y), 0.f);
        o.z = fmaxf(fmaf(v.z, sc.z, sh.z), 0.f);
        o.w = fmaxf(fmaf(v.w, sc.w, sh.w), 0.f);
        *(float4*)(&lh[r][k4]) = o;
    }
    __syncthreads();
    const int cg = tid & 7;
    const int rl = tid >> 3;
    #pragma unroll
    for (int p = 0; p < 2; ++p) {
        int r = p * 32 + rl;
        int grow = row0 + r;
        float ax = 0.f, ay = 0.f, az = 0.f, aw = 0.f;
        #pragma unroll
        for (int k = 0; k < 64; ++k) {
            float hv = lh[r][k];
            float4 wv = *(const float4*)(&lw[k][cg << 2]);
            ax = fmaf(hv, wv.x, ax); ay = fmaf(hv, wv.y, ay);
            az = fmaf(hv, wv.z, az); aw = fmaf(hv, wv.w, aw);
        }
        if (grow < NN) {
            int c = cg << 2;
            if (c < 16) {
                ushort4 o;
                o.x = f2bf(ax); o.y = f2bf(ay); o.z = f2bf(az); o.w = f2bf(aw);
                *(ushort4*)(y2 + (size_t)grow * 16 + c) = o;
            } else {
                *(float4*)(hr2 + (size_t)grow * 16 + (c - 16)) = make_float4(ax, ay, az, aw);
            }
        }
    }
}

// ---------------- gather2 + epilogue: emb + logits straight to d_out -------------
__global__ __launch_bounds__(256) void k_gather2(const unsigned short* __restrict__ y2,
        const int* __restrict__ rowptr, const int* __restrict__ eidx,
        const float* __restrict__ hr2, const float* __restrict__ b2l,
        const float* __restrict__ deg_inv, const float* __restrict__ Wc,
        const float* __restrict__ bc, float* __restrict__ out) {
    const int tid = threadIdx.x;
    const int f = tid & 15, g = tid >> 4;
    const float wc0 = Wc[f], wc1 = Wc[16 + f];
    const float bias = b2l[f];
    for (int n = blockIdx.x * 16 + g; n < NN; n += gridDim.x * 16) {
        int beg = rowptr[n], end = rowptr[n + 1];
        float s0 = 0.f, s1 = 0.f, s2 = 0.f, s3 = 0.f;
        int j = beg;
        for (; j + 3 < end; j += 4) {
            int i0 = eidx[j], i1 = eidx[j + 1], i2 = eidx[j + 2], i3 = eidx[j + 3];
            s0 += bf2f(y2[(size_t)i0 * 16 + f]);
            s1 += bf2f(y2[(size_t)i1 * 16 + f]);
            s2 += bf2f(y2[(size_t)i2 * 16 + f]);
            s3 += bf2f(y2[(size_t)i3 * 16 + f]);
        }
        for (; j < end; ++j) s0 += bf2f(y2[(size_t)eidx[j] * 16 + f]);
        float e = fmaf((s0 + s1) + (s2 + s3), deg_inv[n], hr2[(size_t)n * 16 + f] + bias);
        out[(size_t)(2 * NN) + (size_t)n * 16 + f] = e;
        float l0 = e * wc0, l1 = e * wc1;
        #pragma unroll
        for (int m = 1; m < 16; m <<= 1) {
            l0 += __shfl_xor(l0, m, 64);
            l1 += __shfl_xor(l1, m, 64);
        }
        if (f == 0) {
            out[(size_t)n * 2]     = l0 + bc[0];
            out[(size_t)n * 2 + 1] = l1 + bc[1];
        }
    }
}

extern "C" void kernel_launch(void* const* d_in, const int* in_sizes, int n_in,
                              void* d_out, int out_size, void* d_ws, size_t ws_size,
                              hipStream_t stream) {
    const float* x     = (const float*)d_in[0];
    const int*   src   = (const int*)d_in[1];
    const int*   dst   = (const int*)d_in[2];
    const float* W1l   = (const float*)d_in[3];
    const float* b1l   = (const float*)d_in[4];
    const float* W1r   = (const float*)d_in[5];
    const float* gamma = (const float*)d_in[6];
    const float* beta  = (const float*)d_in[7];
    const float* W2l   = (const float*)d_in[8];
    const float* b2l   = (const float*)d_in[9];
    const float* W2r   = (const float*)d_in[10];
    const float* Wc    = (const float*)d_in[11];
    const float* bc    = (const float*)d_in[12];
    const int E = in_sizes[1];

    // ---- workspace layout (floats) ----------------------------------------------
    // rowptr[100352] | deg_inv[100352] | stats[256] | deg_i[100352] | cursor[100352]
    // | eidx[E] | y1 region[NN*64 fl] (bf16 y1 uses half) | h[NN*64]
    // overlays: bsum in eidx region; y2(bf16)/hr2 reuse y1 region after gather1.
    float* ws      = (float*)d_ws;
    int*   rowptr  = (int*)ws;
    float* deg_inv = ws + 100352;
    float* stats   = ws + 200704;
    int*   deg_i   = (int*)(ws + 200960);
    int*   cursor  = (int*)(ws + 301312);
    int*   eidx    = (int*)(ws + 401664);
    float* y1reg   = ws + 401664 + (size_t)E;
    float* h       = y1reg + (size_t)NN * 64;
    unsigned short* y1 = (unsigned short*)y1reg;
    int*   bsum    = eidx;
    unsigned short* y2 = (unsigned short*)y1reg;
    float* hr2     = y1reg + (size_t)NN * 8;   // after y2's NN*16 ushorts
    float* out     = (float*)d_out;

    hipMemsetAsync(deg_i, 0, NN * sizeof(int), stream);
    hipMemsetAsync(stats, 0, 256 * sizeof(float), stream);

    k_fusedA<<<6256, 256, 0, stream>>>(x, W1l, dst, deg_i, y1, E);

    k_scanA<<<NB, 256, 0, stream>>>(deg_i, rowptr, bsum);
    k_scanB<<<1, 512, 0, stream>>>(bsum, rowptr, E);
    k_finish<<<NB, 256, 0, stream>>>(rowptr, bsum, deg_i, cursor, deg_inv);

    k_fusedB<<<6256, 256, 0, stream>>>(x, W1r, src, dst, cursor, eidx, h, E);

    k_gather1<<<4096, 256, 0, stream>>>(y1, rowptr, eidx, b1l, deg_inv, h, stats);

    k_gemm2<<<(NN + 63) / 64, 256, 0, stream>>>(h, W2l, W2r, stats, gamma, beta, y2, hr2);

    k_gather2<<<2048, 256, 0, stream>>>(y2, rowptr, eidx, hr2, b2l, deg_inv, Wc, bc, out);
}